// Round 15
// baseline (692.068 us; speedup 1.0000x reference)
//
#include <hip/hip_runtime.h>

#define NN 20000
#define NE 320000
#define CDIM 16
#define MID 32
#define EPSF 1e-8f

#define SCHED_FENCE() __builtin_amdgcn_sched_barrier(0)

// ---- workspace word (4B) offsets ----
// stats stored as DOUBLES: stats1 = 5 doubles spaced 8 doubles (64B) apart
// at words 0..79; stats2 = 6*64 doubles at words 80..847.
#define OFF_DEGI   848         // 20000 int
#define ZERO_WORDS 20848
#define OFF_ROWPTR 20848       // 20001 int
#define OFF_CURSOR 40864       // 20000 int
#define OFF_EORDER 60864       // 320000 int
#define OFF_FW1A   380864      // 192
#define OFF_FW1B   381056      // 192
#define OFF_FC1    381248      // 192
#define OFF_BN2A   381440      // 192
#define OFF_FC2    381632      // 192
#define OFF_FW2T   381824      // 6144
#define OFF_ECACHE 387968      // 1280000 (float4)
#define OFF_H0N    1667968     // 320000
#define OFF_H1N    1987968     // 960000
#define OFF_MSGA0  2947968     // 5120000
#define OFF_MSGA1  8067968     // 15360000
#define OFF_MSGB   23427968    // 2560000 (8 f/edge, padded)

#define Y0C   0.28209479177387814f
#define Y1C   0.4886025119029199f
#define Y2C1  1.0925484305920792f
#define Y2C2  0.31539156525252005f
#define Y2C3  0.5462742152960396f
#define S2C   0.7071067811865476f
#define S6C   0.4082482904638631f
#define K0C   0.16286750396763996f

__device__ __forceinline__ void atomAddF(float* p, float v) {
  unsafeAtomicAdd(p, v);
}
__device__ __forceinline__ void atomAddD(double* p, double v) {
  unsafeAtomicAdd(p, v);
}

// Folded 2-layer MLP with sched_barrier fences between compile-time groups:
// caps the scheduler's LDS-read hoisting (the 256-VGPR culprit).
__device__ __forceinline__ void mlpH_lds(
    const float* __restrict__ a1, const float* __restrict__ b1v,
    const float* __restrict__ c1, const float* __restrict__ c2,
    const float* __restrict__ W2T, float we, float r, float* H) {
  float h[MID];
#pragma unroll
  for (int jg = 0; jg < 2; ++jg) {
#pragma unroll
    for (int jq = 0; jq < 16; ++jq) {
      const int j = jg * 16 + jq;
      h[j] = fmaxf(fmaf(we, a1[j], fmaf(r, b1v[j], c1[j])), 0.0f);
    }
    SCHED_FENCE();
  }
#pragma unroll
  for (int jg = 0; jg < 4; ++jg) {
#pragma unroll
    for (int jq = 0; jq < 8; ++jq) {
      const int j = jg * 8 + jq;
      float acc = c2[j];
#pragma unroll
      for (int i = 0; i < MID; ++i) acc = fmaf(h[i], W2T[j * MID + i], acc);
      H[j] = fmaxf(acc, 0.0f);
    }
    SCHED_FENCE();
  }
}

// ---- pass 1: edge cache + degree histogram + f64 stats (block-reduced) ----
__global__ __launch_bounds__(256) void k_pass1(
    const int* __restrict__ src, const int* __restrict__ dst,
    const float* __restrict__ pos, const float* __restrict__ w,
    float* __restrict__ ws) {
  __shared__ double sred[20];  // [stat][wave]
  double lw = 0, lr = 0, lww = 0, lrr = 0, lwr = 0;
  int* degi = (int*)ws + OFF_DEGI;
  float4* ec = (float4*)(ws + OFF_ECACHE);
  for (int e = blockIdx.x * blockDim.x + threadIdx.x; e < NE;
       e += gridDim.x * blockDim.x) {
    int s = src[e], d = dst[e];
    float dx = pos[3 * d + 0] - pos[3 * s + 0];
    float dy = pos[3 * d + 1] - pos[3 * s + 1];
    float dz = pos[3 * d + 2] - pos[3 * s + 2];
    float r = sqrtf(dx * dx + dy * dy + dz * dz);
    float ri = 1.0f / fmaxf(r, EPSF);
    ec[e] = make_float4(r, dx * ri, dy * ri, dz * ri);
    double we = (double)w[e];
    double rd = (double)r;
    lw += we; lr += rd; lww += we * we; lrr += rd * rd; lwr += we * rd;
    atomicAdd(degi + d, 1);
  }
#pragma unroll
  for (int d = 32; d >= 1; d >>= 1) {
    lw += __shfl_xor(lw, d);
    lr += __shfl_xor(lr, d);
    lww += __shfl_xor(lww, d);
    lrr += __shfl_xor(lrr, d);
    lwr += __shfl_xor(lwr, d);
  }
  int wid = threadIdx.x >> 6;
  if ((threadIdx.x & 63) == 0) {
    sred[0 * 4 + wid] = lw;
    sred[1 * 4 + wid] = lr;
    sred[2 * 4 + wid] = lww;
    sred[3 * 4 + wid] = lrr;
    sred[4 * 4 + wid] = lwr;
  }
  __syncthreads();
  if (threadIdx.x < 5) {
    double v = sred[threadIdx.x * 4 + 0] + sred[threadIdx.x * 4 + 1]
             + sred[threadIdx.x * 4 + 2] + sred[threadIdx.x * 4 + 3];
    atomAddD((double*)ws + threadIdx.x * 8, v);  // 64B-spaced
  }
}

// ---- scan ----
__global__ void k_scan(float* __restrict__ ws) {
  __shared__ int buf[256];
  __shared__ int carry;
  const int* degi = (const int*)ws + OFF_DEGI;
  int* rowptr = (int*)ws + OFF_ROWPTR;
  int* cursor = (int*)ws + OFF_CURSOR;
  int tid = threadIdx.x;
  if (tid == 0) carry = 0;
  __syncthreads();
  for (int base = 0; base < NN; base += 256) {
    int v = (base + tid < NN) ? degi[base + tid] : 0;
    buf[tid] = v;
    __syncthreads();
    for (int off = 1; off < 256; off <<= 1) {
      int t = buf[tid];
      int add = (tid >= off) ? buf[tid - off] : 0;
      __syncthreads();
      buf[tid] = t + add;
      __syncthreads();
    }
    int excl = buf[tid] - v;
    if (base + tid < NN) {
      rowptr[base + tid] = carry + excl;
      cursor[base + tid] = carry + excl;
    }
    __syncthreads();
    if (tid == 255) carry += buf[255];
    __syncthreads();
  }
  if (tid == 0) rowptr[NN] = carry;
}

__global__ __launch_bounds__(256) void k_scatter(
    const int* __restrict__ dst, float* __restrict__ ws) {
  int e = blockIdx.x * blockDim.x + threadIdx.x;
  if (e >= NE) return;
  int* cursor = (int*)ws + OFF_CURSOR;
  int* eorder = (int*)ws + OFF_EORDER;
  int d = dst[e];
  int p = atomicAdd(cursor + d, 1);
  eorder[p] = e;
}

// ---- fin1 (double-precision BN finalize) ----
__global__ void k_fin1(const float* __restrict__ rW1, const float* __restrict__ rb1,
                       const float* __restrict__ rg1, const float* __restrict__ rbe1,
                       float* __restrict__ ws) {
  int t = threadIdx.x;
  int k = t >> 5, j = t & 31;
  const double* s1 = (const double*)ws;
  double Sw = s1[0], Sr = s1[8], Sww = s1[16], Srr = s1[24], Swr = s1[32];
  const double inv = 1.0 / (double)NE;
  double W0 = (double)rW1[k * 64 + j], W1 = (double)rW1[k * 64 + 32 + j];
  double b = (double)rb1[k * 32 + j];
  double mlin = (Sw * W0 + Sr * W1) * inv;
  double mu = mlin + b;
  double ex2 = (Sww * W0 * W0 + Srr * W1 * W1 + 2.0 * Swr * W0 * W1) * inv
             + 2.0 * b * mlin + b * b;
  double var = ex2 - mu * mu;
  double a = (double)rg1[k * 32 + j] / sqrt(var + 1e-5);
  ws[OFF_FW1A + t] = (float)(W0 * a);
  ws[OFF_FW1B + t] = (float)(W1 * a);
  ws[OFF_FC1 + t] = (float)((double)rbe1[k * 32 + j] - mlin * a);
}

// ---- stats2: 2 edges/thread (halves LDS reads per edge, 2x ILP) ----
__global__ __launch_bounds__(256) void k_stats2(
    const float* __restrict__ w,
    const float* __restrict__ rW2, const float* __restrict__ rb2,
    float* __restrict__ ws) {
  const int k = blockIdx.y;
  const int j0 = blockIdx.z * 8;
  __shared__ __align__(16) float sW1a[32], sW1b[32], sc1[32];
  __shared__ __align__(16) float sW2c[256];
  __shared__ float sb2[8];
  int tid = threadIdx.x;
  if (tid < 32) {
    sW1a[tid] = ws[OFF_FW1A + k * 32 + tid];
    sW1b[tid] = ws[OFF_FW1B + k * 32 + tid];
    sc1[tid] = ws[OFF_FC1 + k * 32 + tid];
  }
  if (tid < 8) sb2[tid] = rb2[k * 32 + j0 + tid];
  {
    int jj = tid >> 5, i = tid & 31;
    sW2c[tid] = rW2[k * 1024 + i * 32 + j0 + jj];
  }
  __syncthreads();
  const float4* ec = (const float4*)(ws + OFF_ECACHE);
  float lsum[8], lsq[8];
#pragma unroll
  for (int jj = 0; jj < 8; ++jj) { lsum[jj] = 0.0f; lsq[jj] = 0.0f; }
  const int NP = NE / 2;  // 160000 edge pairs
  for (int p = blockIdx.x * blockDim.x + tid; p < NP;
       p += gridDim.x * blockDim.x) {
    int e0 = 2 * p;
    float r0 = ec[e0].x, r1 = ec[e0 + 1].x;
    float w0 = w[e0], w1 = w[e0 + 1];
    float h0[MID], h1[MID];
#pragma unroll
    for (int jg = 0; jg < 2; ++jg) {
#pragma unroll
      for (int jq = 0; jq < 16; ++jq) {
        const int j = jg * 16 + jq;
        float a = sW1a[j], b = sW1b[j], c = sc1[j];
        h0[j] = fmaxf(fmaf(w0, a, fmaf(r0, b, c)), 0.0f);
        h1[j] = fmaxf(fmaf(w1, a, fmaf(r1, b, c)), 0.0f);
      }
      SCHED_FENCE();
    }
#pragma unroll
    for (int jg = 0; jg < 2; ++jg) {
#pragma unroll
      for (int jq = 0; jq < 4; ++jq) {
        const int jj = jg * 4 + jq;
        float a0 = sb2[jj], a1 = sb2[jj];
#pragma unroll
        for (int i = 0; i < MID; ++i) {
          float wv = sW2c[jj * 32 + i];
          a0 = fmaf(h0[i], wv, a0);
          a1 = fmaf(h1[i], wv, a1);
        }
        lsum[jj] += a0 + a1;
        lsq[jj] = fmaf(a0, a0, fmaf(a1, a1, lsq[jj]));
      }
      SCHED_FENCE();
    }
  }
  double* s2 = (double*)(ws + 80);
#pragma unroll
  for (int jj = 0; jj < 8; ++jj) {
    float v1 = lsum[jj], v2 = lsq[jj];
#pragma unroll
    for (int d = 32; d >= 1; d >>= 1) {
      v1 += __shfl_xor(v1, d);
      v2 += __shfl_xor(v2, d);
    }
    if ((tid & 63) == 0) {
      atomAddD(s2 + k * 64 + j0 + jj, (double)v1);
      atomAddD(s2 + k * 64 + 32 + j0 + jj, (double)v2);
    }
  }
}

__global__ void k_fin2(const float* __restrict__ rb2,
                       const float* __restrict__ rg2, const float* __restrict__ rbe2,
                       float* __restrict__ ws) {
  int t = threadIdx.x;
  int k = t >> 5, j = t & 31;
  const double* s2 = (const double*)(ws + 80);
  const double inv = 1.0 / (double)NE;
  double mu = s2[k * 64 + j] * inv;
  double ex2 = s2[k * 64 + 32 + j] * inv;
  double var = ex2 - mu * mu;
  double a = (double)rg2[t] / sqrt(var + 1e-5);
  ws[OFF_BN2A + t] = (float)a;
  ws[OFF_FC2 + t] = (float)((double)rbe2[t] + ((double)rb2[t] - mu) * a);
}

__global__ __launch_bounds__(256) void k_fold2(const float* __restrict__ rW2,
                                               float* __restrict__ ws) {
  int idx = blockIdx.x * blockDim.x + threadIdx.x;
  if (idx >= 6144) return;
  int k = idx >> 10, rem = idx & 1023;
  int j = rem >> 5, i = rem & 31;
  ws[OFF_FW2T + idx] = rW2[k * 1024 + i * 32 + j] * ws[OFF_BN2A + k * 32 + j];
}

// ---- A0: nets 0,2 -> m0[16] -> msgA0 ----
__global__ __launch_bounds__(256) void k_passA0(
    const int* __restrict__ src,
    const float* __restrict__ cI, const float* __restrict__ vI,
    const float* __restrict__ w,
    const float* __restrict__ w00, const float* __restrict__ b00,
    const float* __restrict__ w10, const float* __restrict__ b10,
    float* __restrict__ ws) {
  __shared__ __align__(16) float sW1a[64], sW1b[64], sc1[64], sc2[64];
  __shared__ __align__(16) float sW2T[2048];
  __shared__ __align__(16) float sP00[512], sP10[512];
  __shared__ float sB00[16], sB10[16];
  int tid = threadIdx.x;
  if (tid < 32) {
    sW1a[tid] = ws[OFF_FW1A + tid];       sW1a[32 + tid] = ws[OFF_FW1A + 64 + tid];
    sW1b[tid] = ws[OFF_FW1B + tid];       sW1b[32 + tid] = ws[OFF_FW1B + 64 + tid];
    sc1[tid]  = ws[OFF_FC1 + tid];        sc1[32 + tid]  = ws[OFF_FC1 + 64 + tid];
    sc2[tid]  = ws[OFF_FC2 + tid];        sc2[32 + tid]  = ws[OFF_FC2 + 64 + tid];
  }
  for (int t = tid; t < 1024; t += 256) {
    sW2T[t] = ws[OFF_FW2T + t];
    sW2T[1024 + t] = ws[OFF_FW2T + 2048 + t];
  }
  for (int t = tid; t < 512; t += 256) {
    int i = t >> 4, co = t & 15;
    sP00[co * 32 + i] = w00[t];
    sP10[co * 32 + i] = w10[t];
  }
  if (tid < 16) { sB00[tid] = b00[tid]; sB10[tid] = b10[tid]; }
  __syncthreads();

  const int* eorder = (const int*)ws + OFF_EORDER;
  const float4* ec = (const float4*)(ws + OFF_ECACHE);
  for (int t = blockIdx.x * blockDim.x + tid; t < NE;
       t += gridDim.x * blockDim.x) {
    int e = eorder[t];
    int s = src[e];
    float4 E4 = ec[e];
    float r = E4.x, ux = E4.y, uy = E4.z, uz = E4.w;
    float we = w[e];
    float cs = cI[s];
    float v0 = vI[3 * s + 0], v1 = vI[3 * s + 1], v2 = vI[3 * s + 2];
    float y10 = Y1C * uy, y11 = Y1C * uz, y12 = Y1C * ux;
    float dY1v = y10 * v0 + y11 * v1 + y12 * v2;
    float H[MID];
    float m0[CDIM];
    mlpH_lds(sW1a, sW1b, sc1, sc2, sW2T, we, r, H);
    float f0 = Y0C * cs;
#pragma unroll
    for (int cg = 0; cg < 4; ++cg) {
#pragma unroll
      for (int cq = 0; cq < 4; ++cq) {
        const int co = cg * 4 + cq;
        float acc = sB00[co];
#pragma unroll
        for (int i = 0; i < MID; ++i) acc = fmaf(H[i], sP00[co * 32 + i], acc);
        m0[co] = acc * f0;
      }
      SCHED_FENCE();
    }
    mlpH_lds(sW1a + 32, sW1b + 32, sc1 + 32, sc2 + 32, sW2T + 1024, we, r, H);
#pragma unroll
    for (int cg = 0; cg < 4; ++cg) {
#pragma unroll
      for (int cq = 0; cq < 4; ++cq) {
        const int co = cg * 4 + cq;
        float acc = sB10[co];
#pragma unroll
        for (int i = 0; i < MID; ++i) acc = fmaf(H[i], sP10[co * 32 + i], acc);
        m0[co] = fmaf(acc, dY1v, m0[co]);
      }
      SCHED_FENCE();
    }
    float4* mp = (float4*)(ws + OFF_MSGA0) + t * 4;
    mp[0] = make_float4(m0[0], m0[1], m0[2], m0[3]);
    mp[1] = make_float4(m0[4], m0[5], m0[6], m0[7]);
    mp[2] = make_float4(m0[8], m0[9], m0[10], m0[11]);
    mp[3] = make_float4(m0[12], m0[13], m0[14], m0[15]);
  }
}

// ---- fused A1: nets 1+3 -> m1[48] -> msgA1 ----
// H1 reduced to ra[16] before H3 is built: peak live set < 128 VGPR
// (132 VGPR was 4 over the 128 occupancy cliff -> 2 waves/SIMD).
__global__ __launch_bounds__(256) void k_passA1(
    const int* __restrict__ src,
    const float* __restrict__ cI, const float* __restrict__ vI,
    const float* __restrict__ w,
    const float* __restrict__ w01, const float* __restrict__ b01,
    const float* __restrict__ w11, const float* __restrict__ b11,
    float* __restrict__ ws) {
  __shared__ __align__(16) float sW1a[64], sW1b[64], sc1[64], sc2[64];
  __shared__ __align__(16) float sW2T[2048];
  __shared__ __align__(16) float sP01[512], sP11[1536];
  __shared__ float sB01[16], sB11[48];
  int tid = threadIdx.x;
  if (tid < 32) {
    sW1a[tid] = ws[OFF_FW1A + 32 + tid];  sW1a[32 + tid] = ws[OFF_FW1A + 96 + tid];
    sW1b[tid] = ws[OFF_FW1B + 32 + tid];  sW1b[32 + tid] = ws[OFF_FW1B + 96 + tid];
    sc1[tid]  = ws[OFF_FC1 + 32 + tid];   sc1[32 + tid]  = ws[OFF_FC1 + 96 + tid];
    sc2[tid]  = ws[OFF_FC2 + 32 + tid];   sc2[32 + tid]  = ws[OFF_FC2 + 96 + tid];
  }
  for (int t = tid; t < 1024; t += 256) {
    sW2T[t] = ws[OFF_FW2T + 1024 + t];
    sW2T[1024 + t] = ws[OFF_FW2T + 3072 + t];
  }
  for (int t = tid; t < 512; t += 256) {
    int i = t >> 4, co = t & 15;
    sP01[co * 32 + i] = w01[t];
  }
  for (int t = tid; t < 1536; t += 256) {
    int i = t / 48, c = t - i * 48;
    sP11[c * 32 + i] = w11[t];
  }
  if (tid < 16) sB01[tid] = b01[tid];
  if (tid < 48) sB11[tid] = b11[tid];
  __syncthreads();

  const int* eorder = (const int*)ws + OFF_EORDER;
  const float4* ec = (const float4*)(ws + OFF_ECACHE);
  for (int t = blockIdx.x * blockDim.x + tid; t < NE;
       t += gridDim.x * blockDim.x) {
    int e = eorder[t];
    int s = src[e];
    float4 E4 = ec[e];
    float r = E4.x, ux = E4.y, uy = E4.z, uz = E4.w;
    float we = w[e];
    float cs = cI[s];
    float v0 = vI[3 * s + 0], v1 = vI[3 * s + 1], v2 = vI[3 * s + 2];
    float y10 = Y1C * uy, y11 = Y1C * uz, y12 = Y1C * ux;
    float y20 = Y2C1 * ux * uy, y21 = Y2C1 * uy * uz;
    float y22 = Y2C2 * (3.0f * uz * uz - 1.0f);
    float y23 = Y2C1 * ux * uz, y24 = Y2C3 * (ux * ux - uy * uy);
    float S00 = -S6C * y22 - S2C * y24;
    float S11 = 2.0f * S6C * y22;
    float S22 = -S6C * y22 + S2C * y24;
    float S01 = S2C * y21, S02 = S2C * y20, S12 = S2C * y23;
    float KV[3][3];
    KV[0][0] = K0C * v0; KV[0][1] = K0C * v1; KV[0][2] = K0C * v2;
    KV[1][0] = S2C * (y12 * v1 - y11 * v2);
    KV[1][1] = S2C * (y10 * v2 - y12 * v0);
    KV[1][2] = S2C * (y11 * v0 - y10 * v1);
    KV[2][0] = S00 * v0 + S01 * v1 + S02 * v2;
    KV[2][1] = S01 * v0 + S11 * v1 + S12 * v2;
    KV[2][2] = S02 * v0 + S12 * v1 + S22 * v2;
    float cy0 = cs * y10, cy1 = cs * y11, cy2 = cs * y12;

    float H[MID];
    float ra[16];
    // phase 1: net1 MLP -> project to ra[16]; H1 dies here
    mlpH_lds(sW1a, sW1b, sc1, sc2, sW2T, we, r, H);
#pragma unroll
    for (int cg = 0; cg < 4; ++cg) {
#pragma unroll
      for (int cq = 0; cq < 4; ++cq) {
        const int co = cg * 4 + cq;
        float acc = sB01[co];
#pragma unroll
        for (int i = 0; i < MID; ++i) acc = fmaf(H[i], sP01[co * 32 + i], acc);
        ra[co] = acc;
      }
      SCHED_FENCE();
    }
    // phase 2: net3 MLP (H reused) -> combine with ra, KV
    mlpH_lds(sW1a + 32, sW1b + 32, sc1 + 32, sc2 + 32, sW2T + 1024, we, r, H);
    float4* mp = (float4*)(ws + OFF_MSGA1) + t * 12;
#pragma unroll 1
    for (int g = 0; g < 4; ++g) {   // rolled: caps live registers
      float a[12];
#pragma unroll
      for (int q = 0; q < 4; ++q) {
        int co = g * 4 + q;
        float R0 = sB11[co * 3 + 0], R1 = sB11[co * 3 + 1], R2 = sB11[co * 3 + 2];
#pragma unroll
        for (int i = 0; i < MID; ++i) {
          float hi = H[i];
          R0 = fmaf(hi, sP11[(co * 3 + 0) * 32 + i], R0);
          R1 = fmaf(hi, sP11[(co * 3 + 1) * 32 + i], R1);
          R2 = fmaf(hi, sP11[(co * 3 + 2) * 32 + i], R2);
        }
        float Ra = ra[co];
        a[q * 3 + 0] = fmaf(Ra, cy0, R0 * KV[0][0] + R1 * KV[1][0] + R2 * KV[2][0]);
        a[q * 3 + 1] = fmaf(Ra, cy1, R0 * KV[0][1] + R1 * KV[1][1] + R2 * KV[2][1]);
        a[q * 3 + 2] = fmaf(Ra, cy2, R0 * KV[0][2] + R1 * KV[1][2] + R2 * KV[2][2]);
      }
      mp[g * 3 + 0] = make_float4(a[0], a[1], a[2], a[3]);
      mp[g * 3 + 1] = make_float4(a[4], a[5], a[6], a[7]);
      mp[g * 3 + 2] = make_float4(a[8], a[9], a[10], a[11]);
      SCHED_FENCE();
    }
  }
}

// ---- nodeA ----
__global__ __launch_bounds__(256) void k_nodeA(
    const float* __restrict__ cI, const float* __restrict__ vI,
    const float* __restrict__ selfA0, const float* __restrict__ selfA1,
    const float* __restrict__ nbias0, const float* __restrict__ nbias1,
    float* __restrict__ ws) {
  int idx = blockIdx.x * blockDim.x + threadIdx.x;
  if (idx >= NN * CDIM) return;
  int n = idx >> 4, co = idx & 15;
  const int* rowptr = (const int*)ws + OFF_ROWPTR;
  int r0 = rowptr[n], r1 = rowptr[n + 1];
  const float* mA0 = ws + OFF_MSGA0;
  const float* mA1 = ws + OFF_MSGA1;
  float x0 = 0.0f, xa = 0.0f, xb = 0.0f, xc = 0.0f;
  for (int row = r0; row < r1; ++row) {
    x0 += mA0[row * 16 + co];
    xa += mA1[row * 48 + co * 3 + 0];
    xb += mA1[row * 48 + co * 3 + 1];
    xc += mA1[row * 48 + co * 3 + 2];
  }
  float dg = (float)(r1 - r0);
  float iv = 1.0f / fmaxf(dg, 1.0f);
  float mk = dg > 0.0f ? 1.0f : 0.0f;
  x0 = x0 * iv + selfA0[co] * cI[n] * mk;
  float n0 = sqrtf(x0 * x0 + 1e-12f);
  ws[OFF_H0N + idx] = fmaxf(n0 + nbias0[co], 0.0f) * (x0 / fmaxf(n0, EPSF));
  xa = xa * iv + selfA1[co] * vI[3 * n + 0] * mk;
  xb = xb * iv + selfA1[co] * vI[3 * n + 1] * mk;
  xc = xc * iv + selfA1[co] * vI[3 * n + 2] * mk;
  float nv = sqrtf(xa * xa + xb * xb + xc * xc + 1e-12f);
  float sc = fmaxf(nv + nbias1[co], 0.0f) / fmaxf(nv, EPSF);
  ws[OFF_H1N + idx * 3 + 0] = xa * sc;
  ws[OFF_H1N + idx * 3 + 1] = xb * sc;
  ws[OFF_H1N + idx * 3 + 2] = xc * sc;
}

// ---- fused B: nets 4+5 -> msgB (single write, ci-outer rolled loops) ----
__global__ __launch_bounds__(256) void k_passB(
    const int* __restrict__ src, const float* __restrict__ w,
    const float* __restrict__ wb01, const float* __restrict__ bb01,
    const float* __restrict__ wb11, const float* __restrict__ bb11,
    float* __restrict__ ws) {
  __shared__ __align__(16) float sW1a[64], sW1b[64], sc1[64], sc2[64];
  __shared__ __align__(16) float sW2T[2048];
  __shared__ __align__(16) float sPB01[1024];  // [(ci*2+o)*32+i]
  __shared__ __align__(16) float sPB11[3072];  // [(ci*6+of)*32+i]
  __shared__ float sBB01[32];                  // [ci*2+o]
  __shared__ float sBB11[96];                  // [ci*6+of]
  int tid = threadIdx.x;
  if (tid < 64) {
    sW1a[tid] = ws[OFF_FW1A + 128 + tid];
    sW1b[tid] = ws[OFF_FW1B + 128 + tid];
    sc1[tid] = ws[OFF_FC1 + 128 + tid];
    sc2[tid] = ws[OFF_FC2 + 128 + tid];
  }
  for (int t = tid; t < 2048; t += 256) sW2T[t] = ws[OFF_FW2T + 4096 + t];
  for (int t = tid; t < 1024; t += 256) {
    int i = t >> 5, c = t & 31;           // c = o*16 + ci
    int o = c >> 4, ci = c & 15;
    sPB01[(ci * 2 + o) * 32 + i] = wb01[t];
  }
  for (int t = tid; t < 3072; t += 256) {
    int i = t / 96, c = t - i * 96;       // c = o*48 + ci*3 + f
    int o = c / 48, rem = c - o * 48;
    int ci = rem / 3, f = rem - ci * 3;
    sPB11[(ci * 6 + o * 3 + f) * 32 + i] = wb11[t];
  }
  if (tid < 32) {
    int o = tid >> 4, ci = tid & 15;
    sBB01[ci * 2 + o] = bb01[tid];
  }
  if (tid < 96) {
    int o = tid / 48, rem = tid - o * 48;
    int ci = rem / 3, f = rem - ci * 3;
    sBB11[ci * 6 + o * 3 + f] = bb11[tid];
  }
  __syncthreads();

  const int* eorder = (const int*)ws + OFF_EORDER;
  const float4* ec = (const float4*)(ws + OFF_ECACHE);
  for (int t = blockIdx.x * blockDim.x + tid; t < NE;
       t += gridDim.x * blockDim.x) {
    int e = eorder[t];
    int s = src[e];
    float4 E4 = ec[e];
    float r = E4.x, ux = E4.y, uy = E4.z, uz = E4.w;
    float we = w[e];
    float y10 = Y1C * uy, y11 = Y1C * uz, y12 = Y1C * ux;
    float y20 = Y2C1 * ux * uy, y21 = Y2C1 * uy * uz;
    float y22 = Y2C2 * (3.0f * uz * uz - 1.0f);
    float y23 = Y2C1 * ux * uz, y24 = Y2C3 * (ux * ux - uy * uy);
    float S00 = -S6C * y22 - S2C * y24;
    float S11 = 2.0f * S6C * y22;
    float S22 = -S6C * y22 + S2C * y24;
    float S01 = S2C * y21, S02 = S2C * y20, S12 = S2C * y23;

    float H[MID];
    // --- net 4: A_o = sum_ci R[o,ci] * h0n[src,ci] ---
    mlpH_lds(sW1a, sW1b, sc1, sc2, sW2T, we, r, H);
    const float* h0p = ws + OFF_H0N + s * CDIM;
    float A0 = 0.0f, A1 = 0.0f;
#pragma unroll 1
    for (int ci = 0; ci < CDIM; ++ci) {   // rolled: 2 chains live
      float b = h0p[ci];
      float R0 = sBB01[ci * 2 + 0];
      float R1 = sBB01[ci * 2 + 1];
#pragma unroll
      for (int i = 0; i < MID; ++i) {
        float hi = H[i];
        R0 = fmaf(hi, sPB01[(ci * 2 + 0) * 32 + i], R0);
        R1 = fmaf(hi, sPB01[(ci * 2 + 1) * 32 + i], R1);
      }
      A0 = fmaf(R0, b, A0);
      A1 = fmaf(R1, b, A1);
      SCHED_FENCE();
    }
    // --- net 5: G[of][b] = sum_ci R[of,ci] * h1n[src,ci,b] ---
    mlpH_lds(sW1a + 32, sW1b + 32, sc1 + 32, sc2 + 32, sW2T + 1024, we, r, H);
    const float* h1p = ws + OFF_H1N + s * CDIM * 3;
    float G[6][3];
#pragma unroll
    for (int of = 0; of < 6; ++of) {
      G[of][0] = 0.0f; G[of][1] = 0.0f; G[of][2] = 0.0f;
    }
#pragma unroll 1
    for (int ci = 0; ci < CDIM; ++ci) {   // rolled: 6 chains live
      float b0 = h1p[ci * 3 + 0], b1 = h1p[ci * 3 + 1], b2 = h1p[ci * 3 + 2];
#pragma unroll
      for (int of = 0; of < 6; ++of) {
        float R = sBB11[ci * 6 + of];
#pragma unroll
        for (int i = 0; i < MID; ++i)
          R = fmaf(H[i], sPB11[(ci * 6 + of) * 32 + i], R);
        G[of][0] = fmaf(R, b0, G[of][0]);
        G[of][1] = fmaf(R, b1, G[of][1]);
        G[of][2] = fmaf(R, b2, G[of][2]);
      }
      SCHED_FENCE();
    }
    // --- epilogue: mB[o] = A_o*Y1 + geometry(G); single write ---
    float4* mp = (float4*)(ws + OFF_MSGB) + t * 2;
#pragma unroll
    for (int o = 0; o < 2; ++o) {
      float Ao = (o == 0) ? A0 : A1;
      float m0 = Ao * y10 + K0C * G[o * 3 + 0][0]
               + S2C * (y12 * G[o * 3 + 1][1] - y11 * G[o * 3 + 1][2])
               + S00 * G[o * 3 + 2][0] + S01 * G[o * 3 + 2][1] + S02 * G[o * 3 + 2][2];
      float m1 = Ao * y11 + K0C * G[o * 3 + 0][1]
               + S2C * (y10 * G[o * 3 + 1][2] - y12 * G[o * 3 + 1][0])
               + S01 * G[o * 3 + 2][0] + S11 * G[o * 3 + 2][1] + S12 * G[o * 3 + 2][2];
      float m2 = Ao * y12 + K0C * G[o * 3 + 0][2]
               + S2C * (y11 * G[o * 3 + 1][0] - y10 * G[o * 3 + 1][1])
               + S02 * G[o * 3 + 2][0] + S12 * G[o * 3 + 2][1] + S22 * G[o * 3 + 2][2];
      mp[o] = make_float4(m0, m1, m2, 0.0f);
    }
  }
}

// ---- nodeB ----
__global__ __launch_bounds__(256) void k_nodeB(
    const float* __restrict__ selfB1, float* __restrict__ out,
    const float* __restrict__ ws) {
  int idx = blockIdx.x * blockDim.x + threadIdx.x;
  if (idx >= NN * 6) return;
  int n = idx / 6;
  int q = idx - n * 6;
  int o = q / 3, a = q - o * 3;
  const int* rowptr = (const int*)ws + OFF_ROWPTR;
  int r0 = rowptr[n], r1 = rowptr[n + 1];
  const float* msgB = ws + OFF_MSGB;
  int col = o * 4 + a;
  float sum = 0.0f;
  for (int row = r0; row < r1; ++row) sum += msgB[row * 8 + col];
  float dg = (float)(r1 - r0);
  float iv = 1.0f / fmaxf(dg, 1.0f);
  float mk = dg > 0.0f ? 1.0f : 0.0f;
  const float* h1p = ws + OFF_H1N + n * CDIM * 3;
  float self = 0.0f;
#pragma unroll
  for (int ci = 0; ci < CDIM; ++ci)
    self = fmaf(selfB1[o * CDIM + ci], h1p[ci * 3 + a], self);
  out[idx] = sum * iv + self * mk;
}

extern "C" void kernel_launch(void* const* d_in, const int* in_sizes, int n_in,
                              void* d_out, int out_size, void* d_ws, size_t ws_size,
                              hipStream_t stream) {
  (void)in_sizes; (void)n_in; (void)out_size; (void)ws_size;
  const int* src = (const int*)d_in[0];
  const int* dst = (const int*)d_in[1];
  const float* pos = (const float*)d_in[2];
  const float* cI = (const float*)d_in[3];
  const float* vI = (const float*)d_in[4];
  const float* w = (const float*)d_in[5];
  const float* rW1 = (const float*)d_in[6];
  const float* rb1 = (const float*)d_in[7];
  const float* rg1 = (const float*)d_in[8];
  const float* rbe1 = (const float*)d_in[9];
  const float* rW2 = (const float*)d_in[10];
  const float* rb2 = (const float*)d_in[11];
  const float* rg2 = (const float*)d_in[12];
  const float* rbe2 = (const float*)d_in[13];
  const float* w3_a00 = (const float*)d_in[14];
  const float* b3_a00 = (const float*)d_in[15];
  const float* w3_a01 = (const float*)d_in[16];
  const float* b3_a01 = (const float*)d_in[17];
  const float* w3_a10 = (const float*)d_in[18];
  const float* b3_a10 = (const float*)d_in[19];
  const float* w3_a11 = (const float*)d_in[20];
  const float* b3_a11 = (const float*)d_in[21];
  const float* w3_b01 = (const float*)d_in[22];
  const float* b3_b01 = (const float*)d_in[23];
  const float* w3_b11 = (const float*)d_in[24];
  const float* b3_b11 = (const float*)d_in[25];
  const float* selfA0 = (const float*)d_in[26];
  const float* selfA1 = (const float*)d_in[27];
  const float* selfB1 = (const float*)d_in[28];
  const float* nbias0 = (const float*)d_in[29];
  const float* nbias1 = (const float*)d_in[30];
  float* ws = (float*)d_ws;
  float* out = (float*)d_out;

  hipMemsetAsync(d_ws, 0, (size_t)ZERO_WORDS * 4, stream);

  k_pass1<<<1250, 256, 0, stream>>>(src, dst, pos, w, ws);
  k_fin1<<<1, 192, 0, stream>>>(rW1, rb1, rg1, rbe1, ws);
  k_scan<<<1, 256, 0, stream>>>(ws);
  k_scatter<<<1250, 256, 0, stream>>>(dst, ws);
  k_stats2<<<dim3(64, 6, 4), 256, 0, stream>>>(w, rW2, rb2, ws);
  k_fin2<<<1, 192, 0, stream>>>(rb2, rg2, rbe2, ws);
  k_fold2<<<24, 256, 0, stream>>>(rW2, ws);
  k_passA0<<<1250, 256, 0, stream>>>(src, cI, vI, w, w3_a00, b3_a00,
                                     w3_a10, b3_a10, ws);
  k_passA1<<<1250, 256, 0, stream>>>(src, cI, vI, w, w3_a01, b3_a01,
                                     w3_a11, b3_a11, ws);
  k_nodeA<<<1250, 256, 0, stream>>>(cI, vI, selfA0, selfA1, nbias0, nbias1, ws);
  k_passB<<<1250, 256, 0, stream>>>(src, w, w3_b01, b3_b01, w3_b11, b3_b11, ws);
  k_nodeB<<<469, 256, 0, stream>>>(selfB1, out, ws);
}

// Round 16
// 670.440 us; speedup vs baseline: 1.0323x; 1.0323x over previous
//
#include <hip/hip_runtime.h>

#define NN 20000
#define NE 320000
#define CDIM 16
#define MID 32
#define EPSF 1e-8f

#define SCHED_FENCE() __builtin_amdgcn_sched_barrier(0)

// ---- workspace word (4B) offsets ----
// stats stored as DOUBLES: stats1 = 5 doubles spaced 8 doubles (64B) apart
// at words 0..79; stats2 = 6*64 doubles at words 80..847.
#define OFF_DEGI   848         // 20000 int
#define ZERO_WORDS 20848
#define OFF_ROWPTR 20848       // 20001 int
#define OFF_CURSOR 40864       // 20000 int
#define OFF_EORDER 60864       // 320000 int
#define OFF_SRCS   380864      // 320000 int  (src in sorted order)
#define OFF_WSRT   700864      // 320000 f    (w in sorted order)
#define OFF_FW1A   1020864     // 192
#define OFF_FW1B   1021056     // 192
#define OFF_FC1    1021248     // 192
#define OFF_BN2A   1021440     // 192
#define OFF_FC2    1021632     // 192
#define OFF_FW2T   1021824     // 6144
#define OFF_ECS    1027968     // 1280000 (float4: r,ux,uy,uz — SORTED order)
#define OFF_H0N    2307968     // 320000
#define OFF_H1N    2627968     // 960000
#define OFF_MSGA0  3587968     // 5120000
#define OFF_MSGA1  8707968     // 15360000
#define OFF_MSGB   24067968    // 2560000 (8 f/edge, padded)
// total 26627968 words ~ 106.5 MB

#define Y0C   0.28209479177387814f
#define Y1C   0.4886025119029199f
#define Y2C1  1.0925484305920792f
#define Y2C2  0.31539156525252005f
#define Y2C3  0.5462742152960396f
#define S2C   0.7071067811865476f
#define S6C   0.4082482904638631f
#define K0C   0.16286750396763996f

__device__ __forceinline__ void atomAddF(float* p, float v) {
  unsafeAtomicAdd(p, v);
}
__device__ __forceinline__ void atomAddD(double* p, double v) {
  unsafeAtomicAdd(p, v);
}

// Folded 2-layer MLP with sched_barrier fences between compile-time groups.
__device__ __forceinline__ void mlpH_lds(
    const float* __restrict__ a1, const float* __restrict__ b1v,
    const float* __restrict__ c1, const float* __restrict__ c2,
    const float* __restrict__ W2T, float we, float r, float* H) {
  float h[MID];
#pragma unroll
  for (int jg = 0; jg < 2; ++jg) {
#pragma unroll
    for (int jq = 0; jq < 16; ++jq) {
      const int j = jg * 16 + jq;
      h[j] = fmaxf(fmaf(we, a1[j], fmaf(r, b1v[j], c1[j])), 0.0f);
    }
    SCHED_FENCE();
  }
#pragma unroll
  for (int jg = 0; jg < 4; ++jg) {
#pragma unroll
    for (int jq = 0; jq < 8; ++jq) {
      const int j = jg * 8 + jq;
      float acc = c2[j];
#pragma unroll
      for (int i = 0; i < MID; ++i) acc = fmaf(h[i], W2T[j * MID + i], acc);
      H[j] = fmaxf(acc, 0.0f);
    }
    SCHED_FENCE();
  }
}

// ---- pass 1: degree histogram only ----
__global__ __launch_bounds__(256) void k_hist(
    const int* __restrict__ dst, float* __restrict__ ws) {
  int e = blockIdx.x * blockDim.x + threadIdx.x;
  if (e >= NE) return;
  atomicAdd((int*)ws + OFF_DEGI + dst[e], 1);
}

// ---- scan ----
__global__ void k_scan(float* __restrict__ ws) {
  __shared__ int buf[256];
  __shared__ int carry;
  const int* degi = (const int*)ws + OFF_DEGI;
  int* rowptr = (int*)ws + OFF_ROWPTR;
  int* cursor = (int*)ws + OFF_CURSOR;
  int tid = threadIdx.x;
  if (tid == 0) carry = 0;
  __syncthreads();
  for (int base = 0; base < NN; base += 256) {
    int v = (base + tid < NN) ? degi[base + tid] : 0;
    buf[tid] = v;
    __syncthreads();
    for (int off = 1; off < 256; off <<= 1) {
      int t = buf[tid];
      int add = (tid >= off) ? buf[tid - off] : 0;
      __syncthreads();
      buf[tid] = t + add;
      __syncthreads();
    }
    int excl = buf[tid] - v;
    if (base + tid < NN) {
      rowptr[base + tid] = carry + excl;
      cursor[base + tid] = carry + excl;
    }
    __syncthreads();
    if (tid == 255) carry += buf[255];
    __syncthreads();
  }
  if (tid == 0) rowptr[NN] = carry;
}

__global__ __launch_bounds__(256) void k_scatter(
    const int* __restrict__ dst, float* __restrict__ ws) {
  int e = blockIdx.x * blockDim.x + threadIdx.x;
  if (e >= NE) return;
  int* cursor = (int*)ws + OFF_CURSOR;
  int* eorder = (int*)ws + OFF_EORDER;
  int d = dst[e];
  int p = atomicAdd(cursor + d, 1);
  eorder[p] = e;
}

// ---- geo: gather edge data into SORTED order + f64 stats1 ----
// All gathers (src/dst/pos/w) hit small L2-resident tables; outputs
// (ecs/wsrt/srcs) are coalesced. Hot edge kernels then read linearly.
__global__ __launch_bounds__(256) void k_geo(
    const int* __restrict__ src, const int* __restrict__ dst,
    const float* __restrict__ pos, const float* __restrict__ w,
    float* __restrict__ ws) {
  __shared__ double sred[20];
  double lw = 0, lr = 0, lww = 0, lrr = 0, lwr = 0;
  const int* eorder = (const int*)ws + OFF_EORDER;
  int* srcs = (int*)ws + OFF_SRCS;
  float* wsrt = ws + OFF_WSRT;
  float4* ecs = (float4*)(ws + OFF_ECS);
  for (int t = blockIdx.x * blockDim.x + threadIdx.x; t < NE;
       t += gridDim.x * blockDim.x) {
    int e = eorder[t];
    int s = src[e], d = dst[e];
    float dx = pos[3 * d + 0] - pos[3 * s + 0];
    float dy = pos[3 * d + 1] - pos[3 * s + 1];
    float dz = pos[3 * d + 2] - pos[3 * s + 2];
    float r = sqrtf(dx * dx + dy * dy + dz * dz);
    float ri = 1.0f / fmaxf(r, EPSF);
    ecs[t] = make_float4(r, dx * ri, dy * ri, dz * ri);
    float we = w[e];
    wsrt[t] = we;
    srcs[t] = s;
    double wd = (double)we, rd = (double)r;
    lw += wd; lr += rd; lww += wd * wd; lrr += rd * rd; lwr += wd * rd;
  }
#pragma unroll
  for (int d = 32; d >= 1; d >>= 1) {
    lw += __shfl_xor(lw, d);
    lr += __shfl_xor(lr, d);
    lww += __shfl_xor(lww, d);
    lrr += __shfl_xor(lrr, d);
    lwr += __shfl_xor(lwr, d);
  }
  int wid = threadIdx.x >> 6;
  if ((threadIdx.x & 63) == 0) {
    sred[0 * 4 + wid] = lw;
    sred[1 * 4 + wid] = lr;
    sred[2 * 4 + wid] = lww;
    sred[3 * 4 + wid] = lrr;
    sred[4 * 4 + wid] = lwr;
  }
  __syncthreads();
  if (threadIdx.x < 5) {
    double v = sred[threadIdx.x * 4 + 0] + sred[threadIdx.x * 4 + 1]
             + sred[threadIdx.x * 4 + 2] + sred[threadIdx.x * 4 + 3];
    atomAddD((double*)ws + threadIdx.x * 8, v);  // 64B-spaced
  }
}

// ---- fin1 (double-precision BN finalize) ----
__global__ void k_fin1(const float* __restrict__ rW1, const float* __restrict__ rb1,
                       const float* __restrict__ rg1, const float* __restrict__ rbe1,
                       float* __restrict__ ws) {
  int t = threadIdx.x;
  int k = t >> 5, j = t & 31;
  const double* s1 = (const double*)ws;
  double Sw = s1[0], Sr = s1[8], Sww = s1[16], Srr = s1[24], Swr = s1[32];
  const double inv = 1.0 / (double)NE;
  double W0 = (double)rW1[k * 64 + j], W1 = (double)rW1[k * 64 + 32 + j];
  double b = (double)rb1[k * 32 + j];
  double mlin = (Sw * W0 + Sr * W1) * inv;
  double mu = mlin + b;
  double ex2 = (Sww * W0 * W0 + Srr * W1 * W1 + 2.0 * Swr * W0 * W1) * inv
             + 2.0 * b * mlin + b * b;
  double var = ex2 - mu * mu;
  double a = (double)rg1[k * 32 + j] / sqrt(var + 1e-5);
  ws[OFF_FW1A + t] = (float)(W0 * a);
  ws[OFF_FW1B + t] = (float)(W1 * a);
  ws[OFF_FC1 + t] = (float)((double)rbe1[k * 32 + j] - mlin * a);
}

// ---- stats2: 2 edges/thread, sorted linear reads ----
__global__ __launch_bounds__(256) void k_stats2(
    const float* __restrict__ rW2, const float* __restrict__ rb2,
    float* __restrict__ ws) {
  const int k = blockIdx.y;
  const int j0 = blockIdx.z * 8;
  __shared__ __align__(16) float sW1a[32], sW1b[32], sc1[32];
  __shared__ __align__(16) float sW2c[256];
  __shared__ float sb2[8];
  int tid = threadIdx.x;
  if (tid < 32) {
    sW1a[tid] = ws[OFF_FW1A + k * 32 + tid];
    sW1b[tid] = ws[OFF_FW1B + k * 32 + tid];
    sc1[tid] = ws[OFF_FC1 + k * 32 + tid];
  }
  if (tid < 8) sb2[tid] = rb2[k * 32 + j0 + tid];
  {
    int jj = tid >> 5, i = tid & 31;
    sW2c[tid] = rW2[k * 1024 + i * 32 + j0 + jj];
  }
  __syncthreads();
  const float4* ecs = (const float4*)(ws + OFF_ECS);
  const float* wsrt = ws + OFF_WSRT;
  float lsum[8], lsq[8];
#pragma unroll
  for (int jj = 0; jj < 8; ++jj) { lsum[jj] = 0.0f; lsq[jj] = 0.0f; }
  const int NP = NE / 2;
  for (int p = blockIdx.x * blockDim.x + tid; p < NP;
       p += gridDim.x * blockDim.x) {
    int e0 = 2 * p;
    float r0 = ecs[e0].x, r1 = ecs[e0 + 1].x;
    float w0 = wsrt[e0], w1 = wsrt[e0 + 1];
    float h0[MID], h1[MID];
#pragma unroll
    for (int jg = 0; jg < 2; ++jg) {
#pragma unroll
      for (int jq = 0; jq < 16; ++jq) {
        const int j = jg * 16 + jq;
        float a = sW1a[j], b = sW1b[j], c = sc1[j];
        h0[j] = fmaxf(fmaf(w0, a, fmaf(r0, b, c)), 0.0f);
        h1[j] = fmaxf(fmaf(w1, a, fmaf(r1, b, c)), 0.0f);
      }
      SCHED_FENCE();
    }
#pragma unroll
    for (int jg = 0; jg < 2; ++jg) {
#pragma unroll
      for (int jq = 0; jq < 4; ++jq) {
        const int jj = jg * 4 + jq;
        float a0 = sb2[jj], a1 = sb2[jj];
#pragma unroll
        for (int i = 0; i < MID; ++i) {
          float wv = sW2c[jj * 32 + i];
          a0 = fmaf(h0[i], wv, a0);
          a1 = fmaf(h1[i], wv, a1);
        }
        lsum[jj] += a0 + a1;
        lsq[jj] = fmaf(a0, a0, fmaf(a1, a1, lsq[jj]));
      }
      SCHED_FENCE();
    }
  }
  double* s2 = (double*)(ws + 80);
#pragma unroll
  for (int jj = 0; jj < 8; ++jj) {
    float v1 = lsum[jj], v2 = lsq[jj];
#pragma unroll
    for (int d = 32; d >= 1; d >>= 1) {
      v1 += __shfl_xor(v1, d);
      v2 += __shfl_xor(v2, d);
    }
    if ((tid & 63) == 0) {
      atomAddD(s2 + k * 64 + j0 + jj, (double)v1);
      atomAddD(s2 + k * 64 + 32 + j0 + jj, (double)v2);
    }
  }
}

__global__ void k_fin2(const float* __restrict__ rb2,
                       const float* __restrict__ rg2, const float* __restrict__ rbe2,
                       float* __restrict__ ws) {
  int t = threadIdx.x;
  int k = t >> 5, j = t & 31;
  const double* s2 = (const double*)(ws + 80);
  const double inv = 1.0 / (double)NE;
  double mu = s2[k * 64 + j] * inv;
  double ex2 = s2[k * 64 + 32 + j] * inv;
  double var = ex2 - mu * mu;
  double a = (double)rg2[t] / sqrt(var + 1e-5);
  ws[OFF_BN2A + t] = (float)a;
  ws[OFF_FC2 + t] = (float)((double)rbe2[t] + ((double)rb2[t] - mu) * a);
}

__global__ __launch_bounds__(256) void k_fold2(const float* __restrict__ rW2,
                                               float* __restrict__ ws) {
  int idx = blockIdx.x * blockDim.x + threadIdx.x;
  if (idx >= 6144) return;
  int k = idx >> 10, rem = idx & 1023;
  int j = rem >> 5, i = rem & 31;
  ws[OFF_FW2T + idx] = rW2[k * 1024 + i * 32 + j] * ws[OFF_BN2A + k * 32 + j];
}

// ---- A0: nets 0,2 -> m0[16] -> msgA0 (all linear reads) ----
__global__ __launch_bounds__(256) void k_passA0(
    const float* __restrict__ cI, const float* __restrict__ vI,
    const float* __restrict__ w00, const float* __restrict__ b00,
    const float* __restrict__ w10, const float* __restrict__ b10,
    float* __restrict__ ws) {
  __shared__ __align__(16) float sW1a[64], sW1b[64], sc1[64], sc2[64];
  __shared__ __align__(16) float sW2T[2048];
  __shared__ __align__(16) float sP00[512], sP10[512];
  __shared__ float sB00[16], sB10[16];
  int tid = threadIdx.x;
  if (tid < 32) {
    sW1a[tid] = ws[OFF_FW1A + tid];       sW1a[32 + tid] = ws[OFF_FW1A + 64 + tid];
    sW1b[tid] = ws[OFF_FW1B + tid];       sW1b[32 + tid] = ws[OFF_FW1B + 64 + tid];
    sc1[tid]  = ws[OFF_FC1 + tid];        sc1[32 + tid]  = ws[OFF_FC1 + 64 + tid];
    sc2[tid]  = ws[OFF_FC2 + tid];        sc2[32 + tid]  = ws[OFF_FC2 + 64 + tid];
  }
  for (int t = tid; t < 1024; t += 256) {
    sW2T[t] = ws[OFF_FW2T + t];
    sW2T[1024 + t] = ws[OFF_FW2T + 2048 + t];
  }
  for (int t = tid; t < 512; t += 256) {
    int i = t >> 4, co = t & 15;
    sP00[co * 32 + i] = w00[t];
    sP10[co * 32 + i] = w10[t];
  }
  if (tid < 16) { sB00[tid] = b00[tid]; sB10[tid] = b10[tid]; }
  __syncthreads();

  const int* srcs = (const int*)ws + OFF_SRCS;
  const float* wsrt = ws + OFF_WSRT;
  const float4* ecs = (const float4*)(ws + OFF_ECS);
  for (int t = blockIdx.x * blockDim.x + tid; t < NE;
       t += gridDim.x * blockDim.x) {
    int s = srcs[t];
    float4 E4 = ecs[t];
    float r = E4.x, ux = E4.y, uy = E4.z, uz = E4.w;
    float we = wsrt[t];
    float cs = cI[s];
    float v0 = vI[3 * s + 0], v1 = vI[3 * s + 1], v2 = vI[3 * s + 2];
    float y10 = Y1C * uy, y11 = Y1C * uz, y12 = Y1C * ux;
    float dY1v = y10 * v0 + y11 * v1 + y12 * v2;
    float H[MID];
    float m0[CDIM];
    mlpH_lds(sW1a, sW1b, sc1, sc2, sW2T, we, r, H);
    float f0 = Y0C * cs;
#pragma unroll
    for (int cg = 0; cg < 4; ++cg) {
#pragma unroll
      for (int cq = 0; cq < 4; ++cq) {
        const int co = cg * 4 + cq;
        float acc = sB00[co];
#pragma unroll
        for (int i = 0; i < MID; ++i) acc = fmaf(H[i], sP00[co * 32 + i], acc);
        m0[co] = acc * f0;
      }
      SCHED_FENCE();
    }
    mlpH_lds(sW1a + 32, sW1b + 32, sc1 + 32, sc2 + 32, sW2T + 1024, we, r, H);
#pragma unroll
    for (int cg = 0; cg < 4; ++cg) {
#pragma unroll
      for (int cq = 0; cq < 4; ++cq) {
        const int co = cg * 4 + cq;
        float acc = sB10[co];
#pragma unroll
        for (int i = 0; i < MID; ++i) acc = fmaf(H[i], sP10[co * 32 + i], acc);
        m0[co] = fmaf(acc, dY1v, m0[co]);
      }
      SCHED_FENCE();
    }
    float4* mp = (float4*)(ws + OFF_MSGA0) + t * 4;
    mp[0] = make_float4(m0[0], m0[1], m0[2], m0[3]);
    mp[1] = make_float4(m0[4], m0[5], m0[6], m0[7]);
    mp[2] = make_float4(m0[8], m0[9], m0[10], m0[11]);
    mp[3] = make_float4(m0[12], m0[13], m0[14], m0[15]);
  }
}

// ---- fused A1: nets 1+3 -> m1[48] -> msgA1 (all linear reads) ----
__global__ __launch_bounds__(256) void k_passA1(
    const float* __restrict__ cI, const float* __restrict__ vI,
    const float* __restrict__ w01, const float* __restrict__ b01,
    const float* __restrict__ w11, const float* __restrict__ b11,
    float* __restrict__ ws) {
  __shared__ __align__(16) float sW1a[64], sW1b[64], sc1[64], sc2[64];
  __shared__ __align__(16) float sW2T[2048];
  __shared__ __align__(16) float sP01[512], sP11[1536];
  __shared__ float sB01[16], sB11[48];
  int tid = threadIdx.x;
  if (tid < 32) {
    sW1a[tid] = ws[OFF_FW1A + 32 + tid];  sW1a[32 + tid] = ws[OFF_FW1A + 96 + tid];
    sW1b[tid] = ws[OFF_FW1B + 32 + tid];  sW1b[32 + tid] = ws[OFF_FW1B + 96 + tid];
    sc1[tid]  = ws[OFF_FC1 + 32 + tid];   sc1[32 + tid]  = ws[OFF_FC1 + 96 + tid];
    sc2[tid]  = ws[OFF_FC2 + 32 + tid];   sc2[32 + tid]  = ws[OFF_FC2 + 96 + tid];
  }
  for (int t = tid; t < 1024; t += 256) {
    sW2T[t] = ws[OFF_FW2T + 1024 + t];
    sW2T[1024 + t] = ws[OFF_FW2T + 3072 + t];
  }
  for (int t = tid; t < 512; t += 256) {
    int i = t >> 4, co = t & 15;
    sP01[co * 32 + i] = w01[t];
  }
  for (int t = tid; t < 1536; t += 256) {
    int i = t / 48, c = t - i * 48;
    sP11[c * 32 + i] = w11[t];
  }
  if (tid < 16) sB01[tid] = b01[tid];
  if (tid < 48) sB11[tid] = b11[tid];
  __syncthreads();

  const int* srcs = (const int*)ws + OFF_SRCS;
  const float* wsrt = ws + OFF_WSRT;
  const float4* ecs = (const float4*)(ws + OFF_ECS);
  for (int t = blockIdx.x * blockDim.x + tid; t < NE;
       t += gridDim.x * blockDim.x) {
    int s = srcs[t];
    float4 E4 = ecs[t];
    float r = E4.x, ux = E4.y, uy = E4.z, uz = E4.w;
    float we = wsrt[t];
    float cs = cI[s];
    float v0 = vI[3 * s + 0], v1 = vI[3 * s + 1], v2 = vI[3 * s + 2];
    float y10 = Y1C * uy, y11 = Y1C * uz, y12 = Y1C * ux;
    float y20 = Y2C1 * ux * uy, y21 = Y2C1 * uy * uz;
    float y22 = Y2C2 * (3.0f * uz * uz - 1.0f);
    float y23 = Y2C1 * ux * uz, y24 = Y2C3 * (ux * ux - uy * uy);
    float S00 = -S6C * y22 - S2C * y24;
    float S11 = 2.0f * S6C * y22;
    float S22 = -S6C * y22 + S2C * y24;
    float S01 = S2C * y21, S02 = S2C * y20, S12 = S2C * y23;
    float KV[3][3];
    KV[0][0] = K0C * v0; KV[0][1] = K0C * v1; KV[0][2] = K0C * v2;
    KV[1][0] = S2C * (y12 * v1 - y11 * v2);
    KV[1][1] = S2C * (y10 * v2 - y12 * v0);
    KV[1][2] = S2C * (y11 * v0 - y10 * v1);
    KV[2][0] = S00 * v0 + S01 * v1 + S02 * v2;
    KV[2][1] = S01 * v0 + S11 * v1 + S12 * v2;
    KV[2][2] = S02 * v0 + S12 * v1 + S22 * v2;
    float cy0 = cs * y10, cy1 = cs * y11, cy2 = cs * y12;

    float H[MID];
    float ra[16];
    // phase 1: net1 MLP -> project to ra[16]
    mlpH_lds(sW1a, sW1b, sc1, sc2, sW2T, we, r, H);
#pragma unroll
    for (int cg = 0; cg < 4; ++cg) {
#pragma unroll
      for (int cq = 0; cq < 4; ++cq) {
        const int co = cg * 4 + cq;
        float acc = sB01[co];
#pragma unroll
        for (int i = 0; i < MID; ++i) acc = fmaf(H[i], sP01[co * 32 + i], acc);
        ra[co] = acc;
      }
      SCHED_FENCE();
    }
    // phase 2: net3 MLP (H reused) -> combine with ra, KV
    mlpH_lds(sW1a + 32, sW1b + 32, sc1 + 32, sc2 + 32, sW2T + 1024, we, r, H);
    float4* mp = (float4*)(ws + OFF_MSGA1) + t * 12;
#pragma unroll 1
    for (int g = 0; g < 4; ++g) {
      float a[12];
#pragma unroll
      for (int q = 0; q < 4; ++q) {
        int co = g * 4 + q;
        float R0 = sB11[co * 3 + 0], R1 = sB11[co * 3 + 1], R2 = sB11[co * 3 + 2];
#pragma unroll
        for (int i = 0; i < MID; ++i) {
          float hi = H[i];
          R0 = fmaf(hi, sP11[(co * 3 + 0) * 32 + i], R0);
          R1 = fmaf(hi, sP11[(co * 3 + 1) * 32 + i], R1);
          R2 = fmaf(hi, sP11[(co * 3 + 2) * 32 + i], R2);
        }
        float Ra = ra[co];
        a[q * 3 + 0] = fmaf(Ra, cy0, R0 * KV[0][0] + R1 * KV[1][0] + R2 * KV[2][0]);
        a[q * 3 + 1] = fmaf(Ra, cy1, R0 * KV[0][1] + R1 * KV[1][1] + R2 * KV[2][1]);
        a[q * 3 + 2] = fmaf(Ra, cy2, R0 * KV[0][2] + R1 * KV[1][2] + R2 * KV[2][2]);
      }
      mp[g * 3 + 0] = make_float4(a[0], a[1], a[2], a[3]);
      mp[g * 3 + 1] = make_float4(a[4], a[5], a[6], a[7]);
      mp[g * 3 + 2] = make_float4(a[8], a[9], a[10], a[11]);
      SCHED_FENCE();
    }
  }
}

// ---- nodeA ----
__global__ __launch_bounds__(256) void k_nodeA(
    const float* __restrict__ cI, const float* __restrict__ vI,
    const float* __restrict__ selfA0, const float* __restrict__ selfA1,
    const float* __restrict__ nbias0, const float* __restrict__ nbias1,
    float* __restrict__ ws) {
  int idx = blockIdx.x * blockDim.x + threadIdx.x;
  if (idx >= NN * CDIM) return;
  int n = idx >> 4, co = idx & 15;
  const int* rowptr = (const int*)ws + OFF_ROWPTR;
  int r0 = rowptr[n], r1 = rowptr[n + 1];
  const float* mA0 = ws + OFF_MSGA0;
  const float* mA1 = ws + OFF_MSGA1;
  float x0 = 0.0f, xa = 0.0f, xb = 0.0f, xc = 0.0f;
  for (int row = r0; row < r1; ++row) {
    x0 += mA0[row * 16 + co];
    xa += mA1[row * 48 + co * 3 + 0];
    xb += mA1[row * 48 + co * 3 + 1];
    xc += mA1[row * 48 + co * 3 + 2];
  }
  float dg = (float)(r1 - r0);
  float iv = 1.0f / fmaxf(dg, 1.0f);
  float mk = dg > 0.0f ? 1.0f : 0.0f;
  x0 = x0 * iv + selfA0[co] * cI[n] * mk;
  float n0 = sqrtf(x0 * x0 + 1e-12f);
  ws[OFF_H0N + idx] = fmaxf(n0 + nbias0[co], 0.0f) * (x0 / fmaxf(n0, EPSF));
  xa = xa * iv + selfA1[co] * vI[3 * n + 0] * mk;
  xb = xb * iv + selfA1[co] * vI[3 * n + 1] * mk;
  xc = xc * iv + selfA1[co] * vI[3 * n + 2] * mk;
  float nv = sqrtf(xa * xa + xb * xb + xc * xc + 1e-12f);
  float sc = fmaxf(nv + nbias1[co], 0.0f) / fmaxf(nv, EPSF);
  ws[OFF_H1N + idx * 3 + 0] = xa * sc;
  ws[OFF_H1N + idx * 3 + 1] = xb * sc;
  ws[OFF_H1N + idx * 3 + 2] = xc * sc;
}

// ---- fused B: nets 4+5 -> msgB (all linear except h0n/h1n gathers) ----
__global__ __launch_bounds__(256) void k_passB(
    const float* __restrict__ wb01, const float* __restrict__ bb01,
    const float* __restrict__ wb11, const float* __restrict__ bb11,
    float* __restrict__ ws) {
  __shared__ __align__(16) float sW1a[64], sW1b[64], sc1[64], sc2[64];
  __shared__ __align__(16) float sW2T[2048];
  __shared__ __align__(16) float sPB01[1024];  // [(ci*2+o)*32+i]
  __shared__ __align__(16) float sPB11[3072];  // [(ci*6+of)*32+i]
  __shared__ float sBB01[32];                  // [ci*2+o]
  __shared__ float sBB11[96];                  // [ci*6+of]
  int tid = threadIdx.x;
  if (tid < 64) {
    sW1a[tid] = ws[OFF_FW1A + 128 + tid];
    sW1b[tid] = ws[OFF_FW1B + 128 + tid];
    sc1[tid] = ws[OFF_FC1 + 128 + tid];
    sc2[tid] = ws[OFF_FC2 + 128 + tid];
  }
  for (int t = tid; t < 2048; t += 256) sW2T[t] = ws[OFF_FW2T + 4096 + t];
  for (int t = tid; t < 1024; t += 256) {
    int i = t >> 5, c = t & 31;           // c = o*16 + ci
    int o = c >> 4, ci = c & 15;
    sPB01[(ci * 2 + o) * 32 + i] = wb01[t];
  }
  for (int t = tid; t < 3072; t += 256) {
    int i = t / 96, c = t - i * 96;       // c = o*48 + ci*3 + f
    int o = c / 48, rem = c - o * 48;
    int ci = rem / 3, f = rem - ci * 3;
    sPB11[(ci * 6 + o * 3 + f) * 32 + i] = wb11[t];
  }
  if (tid < 32) {
    int o = tid >> 4, ci = tid & 15;
    sBB01[ci * 2 + o] = bb01[tid];
  }
  if (tid < 96) {
    int o = tid / 48, rem = tid - o * 48;
    int ci = rem / 3, f = rem - ci * 3;
    sBB11[ci * 6 + o * 3 + f] = bb11[tid];
  }
  __syncthreads();

  const int* srcs = (const int*)ws + OFF_SRCS;
  const float* wsrt = ws + OFF_WSRT;
  const float4* ecs = (const float4*)(ws + OFF_ECS);
  for (int t = blockIdx.x * blockDim.x + tid; t < NE;
       t += gridDim.x * blockDim.x) {
    int s = srcs[t];
    float4 E4 = ecs[t];
    float r = E4.x, ux = E4.y, uy = E4.z, uz = E4.w;
    float we = wsrt[t];
    float y10 = Y1C * uy, y11 = Y1C * uz, y12 = Y1C * ux;
    float y20 = Y2C1 * ux * uy, y21 = Y2C1 * uy * uz;
    float y22 = Y2C2 * (3.0f * uz * uz - 1.0f);
    float y23 = Y2C1 * ux * uz, y24 = Y2C3 * (ux * ux - uy * uy);
    float S00 = -S6C * y22 - S2C * y24;
    float S11 = 2.0f * S6C * y22;
    float S22 = -S6C * y22 + S2C * y24;
    float S01 = S2C * y21, S02 = S2C * y20, S12 = S2C * y23;

    float H[MID];
    // --- net 4 ---
    mlpH_lds(sW1a, sW1b, sc1, sc2, sW2T, we, r, H);
    const float* h0p = ws + OFF_H0N + s * CDIM;
    float A0 = 0.0f, A1 = 0.0f;
#pragma unroll 1
    for (int ci = 0; ci < CDIM; ++ci) {
      float b = h0p[ci];
      float R0 = sBB01[ci * 2 + 0];
      float R1 = sBB01[ci * 2 + 1];
#pragma unroll
      for (int i = 0; i < MID; ++i) {
        float hi = H[i];
        R0 = fmaf(hi, sPB01[(ci * 2 + 0) * 32 + i], R0);
        R1 = fmaf(hi, sPB01[(ci * 2 + 1) * 32 + i], R1);
      }
      A0 = fmaf(R0, b, A0);
      A1 = fmaf(R1, b, A1);
      SCHED_FENCE();
    }
    // --- net 5 ---
    mlpH_lds(sW1a + 32, sW1b + 32, sc1 + 32, sc2 + 32, sW2T + 1024, we, r, H);
    const float* h1p = ws + OFF_H1N + s * CDIM * 3;
    float G[6][3];
#pragma unroll
    for (int of = 0; of < 6; ++of) {
      G[of][0] = 0.0f; G[of][1] = 0.0f; G[of][2] = 0.0f;
    }
#pragma unroll 1
    for (int ci = 0; ci < CDIM; ++ci) {
      float b0 = h1p[ci * 3 + 0], b1 = h1p[ci * 3 + 1], b2 = h1p[ci * 3 + 2];
#pragma unroll
      for (int of = 0; of < 6; ++of) {
        float R = sBB11[ci * 6 + of];
#pragma unroll
        for (int i = 0; i < MID; ++i)
          R = fmaf(H[i], sPB11[(ci * 6 + of) * 32 + i], R);
        G[of][0] = fmaf(R, b0, G[of][0]);
        G[of][1] = fmaf(R, b1, G[of][1]);
        G[of][2] = fmaf(R, b2, G[of][2]);
      }
      SCHED_FENCE();
    }
    float4* mp = (float4*)(ws + OFF_MSGB) + t * 2;
#pragma unroll
    for (int o = 0; o < 2; ++o) {
      float Ao = (o == 0) ? A0 : A1;
      float m0 = Ao * y10 + K0C * G[o * 3 + 0][0]
               + S2C * (y12 * G[o * 3 + 1][1] - y11 * G[o * 3 + 1][2])
               + S00 * G[o * 3 + 2][0] + S01 * G[o * 3 + 2][1] + S02 * G[o * 3 + 2][2];
      float m1 = Ao * y11 + K0C * G[o * 3 + 0][1]
               + S2C * (y10 * G[o * 3 + 1][2] - y12 * G[o * 3 + 1][0])
               + S01 * G[o * 3 + 2][0] + S11 * G[o * 3 + 2][1] + S12 * G[o * 3 + 2][2];
      float m2 = Ao * y12 + K0C * G[o * 3 + 0][2]
               + S2C * (y11 * G[o * 3 + 1][0] - y10 * G[o * 3 + 1][1])
               + S02 * G[o * 3 + 2][0] + S12 * G[o * 3 + 2][1] + S22 * G[o * 3 + 2][2];
      mp[o] = make_float4(m0, m1, m2, 0.0f);
    }
  }
}

// ---- nodeB ----
__global__ __launch_bounds__(256) void k_nodeB(
    const float* __restrict__ selfB1, float* __restrict__ out,
    const float* __restrict__ ws) {
  int idx = blockIdx.x * blockDim.x + threadIdx.x;
  if (idx >= NN * 6) return;
  int n = idx / 6;
  int q = idx - n * 6;
  int o = q / 3, a = q - o * 3;
  const int* rowptr = (const int*)ws + OFF_ROWPTR;
  int r0 = rowptr[n], r1 = rowptr[n + 1];
  const float* msgB = ws + OFF_MSGB;
  int col = o * 4 + a;
  float sum = 0.0f;
  for (int row = r0; row < r1; ++row) sum += msgB[row * 8 + col];
  float dg = (float)(r1 - r0);
  float iv = 1.0f / fmaxf(dg, 1.0f);
  float mk = dg > 0.0f ? 1.0f : 0.0f;
  const float* h1p = ws + OFF_H1N + n * CDIM * 3;
  float self = 0.0f;
#pragma unroll
  for (int ci = 0; ci < CDIM; ++ci)
    self = fmaf(selfB1[o * CDIM + ci], h1p[ci * 3 + a], self);
  out[idx] = sum * iv + self * mk;
}

extern "C" void kernel_launch(void* const* d_in, const int* in_sizes, int n_in,
                              void* d_out, int out_size, void* d_ws, size_t ws_size,
                              hipStream_t stream) {
  (void)in_sizes; (void)n_in; (void)out_size; (void)ws_size;
  const int* src = (const int*)d_in[0];
  const int* dst = (const int*)d_in[1];
  const float* pos = (const float*)d_in[2];
  const float* cI = (const float*)d_in[3];
  const float* vI = (const float*)d_in[4];
  const float* w = (const float*)d_in[5];
  const float* rW1 = (const float*)d_in[6];
  const float* rb1 = (const float*)d_in[7];
  const float* rg1 = (const float*)d_in[8];
  const float* rbe1 = (const float*)d_in[9];
  const float* rW2 = (const float*)d_in[10];
  const float* rb2 = (const float*)d_in[11];
  const float* rg2 = (const float*)d_in[12];
  const float* rbe2 = (const float*)d_in[13];
  const float* w3_a00 = (const float*)d_in[14];
  const float* b3_a00 = (const float*)d_in[15];
  const float* w3_a01 = (const float*)d_in[16];
  const float* b3_a01 = (const float*)d_in[17];
  const float* w3_a10 = (const float*)d_in[18];
  const float* b3_a10 = (const float*)d_in[19];
  const float* w3_a11 = (const float*)d_in[20];
  const float* b3_a11 = (const float*)d_in[21];
  const float* w3_b01 = (const float*)d_in[22];
  const float* b3_b01 = (const float*)d_in[23];
  const float* w3_b11 = (const float*)d_in[24];
  const float* b3_b11 = (const float*)d_in[25];
  const float* selfA0 = (const float*)d_in[26];
  const float* selfA1 = (const float*)d_in[27];
  const float* selfB1 = (const float*)d_in[28];
  const float* nbias0 = (const float*)d_in[29];
  const float* nbias1 = (const float*)d_in[30];
  float* ws = (float*)d_ws;
  float* out = (float*)d_out;

  hipMemsetAsync(d_ws, 0, (size_t)ZERO_WORDS * 4, stream);

  k_hist<<<1250, 256, 0, stream>>>(dst, ws);
  k_scan<<<1, 256, 0, stream>>>(ws);
  k_scatter<<<1250, 256, 0, stream>>>(dst, ws);
  k_geo<<<1250, 256, 0, stream>>>(src, dst, pos, w, ws);
  k_fin1<<<1, 192, 0, stream>>>(rW1, rb1, rg1, rbe1, ws);
  k_stats2<<<dim3(64, 6, 4), 256, 0, stream>>>(rW2, rb2, ws);
  k_fin2<<<1, 192, 0, stream>>>(rb2, rg2, rbe2, ws);
  k_fold2<<<24, 256, 0, stream>>>(rW2, ws);
  k_passA0<<<1250, 256, 0, stream>>>(cI, vI, w3_a00, b3_a00,
                                     w3_a10, b3_a10, ws);
  k_passA1<<<1250, 256, 0, stream>>>(cI, vI, w3_a01, b3_a01,
                                     w3_a11, b3_a11, ws);
  k_nodeA<<<1250, 256, 0, stream>>>(cI, vI, selfA0, selfA1, nbias0, nbias1, ws);
  k_passB<<<1250, 256, 0, stream>>>(w3_b01, b3_b01, w3_b11, b3_b11, ws);
  k_nodeB<<<469, 256, 0, stream>>>(selfB1, out, ws);
}